// Round 18
// baseline (391.228 us; speedup 1.0000x reference)
//
#include <hip/hip_runtime.h>
#include <hip/hip_bf16.h>

typedef unsigned short u16;
typedef __bf16 bf8 __attribute__((ext_vector_type(8)));
typedef float f4 __attribute__((ext_vector_type(4)));

__device__ __forceinline__ u16 f2bf(float f) {
    unsigned int u = __float_as_uint(f);
    u = (u + 0x7fffu + ((u >> 16) & 1u)) >> 16;   // RNE
    return (u16)u;
}

__device__ __forceinline__ void gload16(const u16* g, u16* l) {
    __builtin_amdgcn_global_load_lds((const __attribute__((address_space(1))) void*)g,
                                     (__attribute__((address_space(3))) void*)l, 16, 0, 0);
}

// ------------- [E][R][C] f32 -> [E][C][R] bf16, 64x64 tiles -------------
__global__ void transpose_cvt_kernel(const float* __restrict__ in, u16* __restrict__ out,
                                     int R, int C) {
    __shared__ u16 t[64][71];
    int e = blockIdx.z;
    int c0 = blockIdx.x * 64, r0 = blockIdx.y * 64;
    int tid = threadIdx.x;
    const float* ip = in + (size_t)e * R * C;
    u16* op = out + (size_t)e * R * C;
#pragma unroll
    for (int k = 0; k < 16; ++k) {
        int idx = k * 256 + tid;
        int r = idx >> 6, c = idx & 63;
        t[c][r] = f2bf(ip[(size_t)(r0 + r) * C + c0 + c]);
    }
    __syncthreads();
#pragma unroll
    for (int k = 0; k < 8; ++k) {
        int c = k * 8 + (tid >> 5);
        int rr = (tid & 31) * 2;
        ushort2 v = make_ushort2(t[c][rr], t[c][rr + 1]);
        *(ushort2*)(op + (size_t)(c0 + c) * R + r0 + rr) = v;
    }
}

// ---------- S [7][1040][7] -> ST [1040][52] ----------
__global__ void transpose_S_kernel(const float* __restrict__ S, float* __restrict__ ST) {
    int idx = blockIdx.x * 256 + threadIdx.x;
    if (idx >= 1040 * 52) return;
    int d = idx / 52, c = idx % 52;
    ST[idx] = (c < 49) ? S[(c / 7) * 7280 + d * 7 + (c % 7)] : 0.f;
}

// ---------------- gating (fp32, exact semantics) + fused x->bf16 ----------------
__global__ void gating_kernel(const float* __restrict__ x, const int* __restrict__ scene,
                              const float* __restrict__ ST, const float* __restrict__ semb,
                              float* __restrict__ gate, u16* __restrict__ xb) {
    __shared__ float xc[4][1040];
    __shared__ float Lsh[4][49];
    int wv = threadIdx.x >> 6, lane = threadIdx.x & 63;
    int row = blockIdx.x * 4 + wv;
    float* xcw = xc[wv];
    const float* xr = x + (size_t)row * 1024;
    for (int d = lane; d < 1024; d += 64) xcw[d] = xr[d];
    int sc = scene[row];
    if (lane < 16) xcw[1024 + lane] = semb[sc * 16 + lane];
    __syncthreads();

    u16* xrow = xb + (size_t)row * 1024;
    for (int d = lane * 4; d < 1024; d += 256) {
        ushort4 o;
        o.x = f2bf(xcw[d]);     o.y = f2bf(xcw[d + 1]);
        o.z = f2bf(xcw[d + 2]); o.w = f2bf(xcw[d + 3]);
        *(ushort4*)(xrow + d) = o;
    }

    if (lane < 49) {
        const float* STp = ST + lane;
        float a0 = 0.f, a1 = 0.f, a2 = 0.f, a3 = 0.f;
        for (int d = 0; d < 1040; d += 4) {
            a0 += xcw[d]     * STp[d * 52];
            a1 += xcw[d + 1] * STp[d * 52 + 52];
            a2 += xcw[d + 2] * STp[d * 52 + 104];
            a3 += xcw[d + 3] * STp[d * 52 + 156];
        }
        Lsh[wv][lane] = (a0 + a1) + (a2 + a3);
    }
    __syncthreads();

    if (lane == 0) {
        float logG[7][7], Gsc[7], piS[7], qS[7];
        for (int e = 0; e < 7; e++) {
            float L[7];
            float m = -1e30f;
            for (int s = 0; s < 7; s++) { L[s] = Lsh[wv][s * 7 + e]; m = fmaxf(m, L[s]); }
            float sum = 0.f;
            for (int s = 0; s < 7; s++) sum += expf(L[s] - m);
            float lse = m + logf(sum);
            float qs = 0.f;
            for (int s = 0; s < 7; s++) { logG[e][s] = L[s] - lse; qs += logG[e][s]; }
            piS[e] = logG[e][sc];
            qS[e] = qs;
            Gsc[e] = expf(logG[e][sc]);
        }
        int epi = 0, eqi = 0; float bp = piS[0], bq = qS[0];
        for (int e = 1; e < 7; e++) {
            if (piS[e] <= bp) { bp = piS[e]; epi = e; }
            if (qS[e]  <= bq) { bq = qS[e];  eqi = e; }
        }
        float mg = -1e30f;
        for (int e = 0; e < 7; e++) mg = fmaxf(mg, Gsc[e]);
        float sum = 0.f;
        float ex[7];
        for (int e = 0; e < 7; e++) { ex[e] = expf(Gsc[e] - mg); sum += ex[e]; }
        float inv = 1.f / sum;
        for (int e = 0; e < 7; e++) {
            float g = ex[e] * inv;
            if (e == epi && e == eqi) g = 0.f;
            gate[row * 7 + e] = g;
        }
    }
}

// ================= 8-phase GEMM template (R6-proven structure, persistent) ======
// BM=128, BN=256, BK=64, 512 thr (8 waves 2x4), per-wave 64x64.
// LDS per dbuf: A[128][64] + B[256][64]; 2 dbuf = 96KB -> 1 block/CU, grid 256
// = all blocks co-resident (required for the G2 handoff).
// T2 swizzle (full 3-bit): elem col ^= (row&7)<<3; conflicts = 0 (R6-verified).
// Counted vmcnt: 6 loads/K-tile staged (4 at p0, 2 at p1); vmcnt(4) once per
// K-tile, vmcnt(0) only at final tile / boundary drains.
// G1: nE=7 chained (112 K-tiles), per-expert mid-loop nt-store of the H-slab.
// G2 balanced split (104/120 K-tiles):
//   producer (grp0): e3 K[0:512) FIRST -> publish raw partial + flagA (~12us),
//                    then e0,e1,e2 gate-folded -> publish fin + flagB (~128us).
//   consumer (grp1): e4,e5,e6 gate-folded, then e3 K[512:2048) LAST; merge
//                    producer's raw e3 partial PRE-relu, fold; merge fin; write
//                    both T-slices. Both flags set before they are checked.
// Sync: R17-proven AGENT-scope release/acquire (cross-XCD safe, replay-safe).
template<bool G2>
__global__ __launch_bounds__(512, 2) void gemm8p_kernel(
    const u16* __restrict__ Abase, const u16* __restrict__ Bbase,
    const float* __restrict__ bias, const float* __restrict__ gate,
    void* __restrict__ outp, float* __restrict__ part3, float* __restrict__ partF,
    int* __restrict__ flags)
{
    constexpr int M = 4096;
    constexpr int K = G2 ? 2048 : 1024;
    constexpr int N = G2 ? 1024 : 2048;

    extern __shared__ u16 lds[];

    const int tid = threadIdx.x;
    const int lane = tid & 63;
    const int wid = tid >> 6;
    const int wr = wid >> 2, wc = wid & 3;
    const int ln15 = lane & 15, lnk = (lane >> 4) * 8;

    int bm, bn, grp, NTtot;
    if constexpr (G2) {
        int id = blockIdx.x;
        int xcd = id & 7, slot = id >> 3;
        grp = xcd & 1;                  // 0: producer, 1: consumer
        bn = slot & 3;
        bm = (slot >> 2) * 4 + (xcd >> 1);
        NTtot = grp ? 120 : 104;
    } else {
        int xcd = blockIdx.x & 7, slot = blockIdx.x >> 3;
        bn = slot >> 2;
        bm = (slot & 3) * 8 + xcd;
        grp = 0; NTtot = 112;
    }
    const int fi = G2 ? (bm * 4 + bn) : 0;

    // gt -> (expert, k-tile) mapping
    auto ekt = [&](int gt, int& e, int& kt) {
        if constexpr (G2) {
            if (grp == 0) {
                if (gt < 8) { e = 3; kt = gt; }                    // e3 K[0:512)
                else        { e = (gt - 8) >> 5; kt = (gt - 8) & 31; }
            } else {
                if (gt < 96) { e = 4 + (gt >> 5); kt = gt & 31; }
                else         { e = 3; kt = gt - 88; }              // e3 K[512:2048)
            }
        } else { e = gt >> 4; kt = gt & 15; }
    };

    const int sr = tid >> 3;
    const int sc = (tid & 7) * 8;

    auto stageA = [&](int gt, int buf) {
        int e, kt; ekt(gt, e, kt);
#pragma unroll
        for (int l = 0; l < 2; ++l) {
            int r = l * 64 + sr;
            int cs = sc ^ ((r & 7) << 3);
            const u16* g = Abase + (G2 ? (size_t)e * M * K : (size_t)0)
                         + (size_t)(bm * 128 + r) * K + kt * 64 + cs;
            gload16(g, lds + buf * 24576 + l * 4096 + tid * 8);
        }
    };
    auto stageB = [&](int gt, int buf, int h) {
        int e, kt; ekt(gt, e, kt);
#pragma unroll
        for (int l = 0; l < 2; ++l) {
            int rb = h * 128 + l * 64 + sr;
            int cs = sc ^ ((rb & 7) << 3);
            const u16* g = Bbase + (size_t)e * N * K
                         + (size_t)(bn * 256 + rb) * K + kt * 64 + cs;
            gload16(g, lds + buf * 24576 + 8192 + h * 8192 + l * 4096 + tid * 8);
        }
    };
    auto aoff = [&](int mi, int ks) {
        int r = wr * 64 + mi * 16 + ln15;
        int c = ks * 32 + lnk;
        return r * 64 + (c ^ ((r & 7) << 3));
    };
    auto boff = [&](int ni, int ks) {
        int rb = wc * 64 + ni * 16 + ln15;
        int c = ks * 32 + lnk;
        return rb * 64 + (c ^ ((rb & 7) << 3));
    };

    f4 acc[4][4] = {};
    f4 fin[4][4] = {};
    bf8 aA[2][2], bL[2][2], bH[2][2];

    stageA(0, 0); stageB(0, 0, 0); stageB(0, 0, 1);

    for (int gt = 0; gt < NTtot; ++gt) {
        const int cur = gt & 1, nxt = cur ^ 1;
        const bool more = (gt + 1 < NTtot);
        const u16* Ac = lds + cur * 24576;
        const u16* Bc = lds + cur * 24576 + 8192;
        // ---------- phase 0
        if (more) {
            stageA(gt + 1, nxt); stageB(gt + 1, nxt, 0);
            asm volatile("s_waitcnt vmcnt(4)" ::: "memory");
        } else {
            asm volatile("s_waitcnt vmcnt(0)" ::: "memory");
        }
        __builtin_amdgcn_sched_barrier(0);
        __builtin_amdgcn_s_barrier();
        __builtin_amdgcn_sched_barrier(0);
#pragma unroll
        for (int mi = 0; mi < 2; ++mi)
#pragma unroll
            for (int ks = 0; ks < 2; ++ks)
                aA[mi][ks] = *(const bf8*)(Ac + aoff(mi, ks));
#pragma unroll
        for (int ni = 0; ni < 2; ++ni)
#pragma unroll
            for (int ks = 0; ks < 2; ++ks)
                bL[ni][ks] = *(const bf8*)(Bc + boff(ni, ks));
        asm volatile("s_waitcnt lgkmcnt(0)" ::: "memory");
        __builtin_amdgcn_sched_barrier(0);
        __builtin_amdgcn_s_setprio(1);
#pragma unroll
        for (int mi = 0; mi < 2; ++mi)
#pragma unroll
            for (int ni = 0; ni < 2; ++ni)
#pragma unroll
                for (int ks = 0; ks < 2; ++ks)
                    acc[mi][ni] = __builtin_amdgcn_mfma_f32_16x16x32_bf16(aA[mi][ks], bL[ni][ks], acc[mi][ni], 0, 0, 0);
        __builtin_amdgcn_s_setprio(0);
        // ---------- phase 1
        if (more) stageB(gt + 1, nxt, 1);
#pragma unroll
        for (int ni = 0; ni < 2; ++ni)
#pragma unroll
            for (int ks = 0; ks < 2; ++ks)
                bH[ni][ks] = *(const bf8*)(Bc + boff(2 + ni, ks));
        asm volatile("s_waitcnt lgkmcnt(0)" ::: "memory");
        __builtin_amdgcn_sched_barrier(0);
        __builtin_amdgcn_s_setprio(1);
#pragma unroll
        for (int mi = 0; mi < 2; ++mi)
#pragma unroll
            for (int ni = 0; ni < 2; ++ni)
#pragma unroll
                for (int ks = 0; ks < 2; ++ks)
                    acc[mi][2 + ni] = __builtin_amdgcn_mfma_f32_16x16x32_bf16(aA[mi][ks], bH[ni][ks], acc[mi][2 + ni], 0, 0, 0);
        __builtin_amdgcn_s_setprio(0);
        // ---------- phase 2
#pragma unroll
        for (int mi = 0; mi < 2; ++mi)
#pragma unroll
            for (int ks = 0; ks < 2; ++ks)
                aA[mi][ks] = *(const bf8*)(Ac + aoff(2 + mi, ks));
        asm volatile("s_waitcnt lgkmcnt(0)" ::: "memory");
        __builtin_amdgcn_sched_barrier(0);
        __builtin_amdgcn_s_setprio(1);
#pragma unroll
        for (int mi = 0; mi < 2; ++mi)
#pragma unroll
            for (int ni = 0; ni < 2; ++ni)
#pragma unroll
                for (int ks = 0; ks < 2; ++ks)
                    acc[2 + mi][2 + ni] = __builtin_amdgcn_mfma_f32_16x16x32_bf16(aA[mi][ks], bH[ni][ks], acc[2 + mi][2 + ni], 0, 0, 0);
        __builtin_amdgcn_s_setprio(0);
        // ---------- phase 3
        __builtin_amdgcn_sched_barrier(0);
        __builtin_amdgcn_s_barrier();
        __builtin_amdgcn_sched_barrier(0);
        __builtin_amdgcn_s_setprio(1);
#pragma unroll
        for (int mi = 0; mi < 2; ++mi)
#pragma unroll
            for (int ni = 0; ni < 2; ++ni)
#pragma unroll
                for (int ks = 0; ks < 2; ++ks)
                    acc[2 + mi][ni] = __builtin_amdgcn_mfma_f32_16x16x32_bf16(aA[mi][ks], bL[ni][ks], acc[2 + mi][ni], 0, 0, 0);
        __builtin_amdgcn_s_setprio(0);
        __builtin_amdgcn_sched_barrier(0);
        // ---------- expert boundary
        bool bnd;
        if constexpr (G2) bnd = (grp == 0) ? (gt == 7 || gt == 39 || gt == 71 || gt == 103)
                                           : (gt == 31 || gt == 63 || gt == 95);
        else bnd = ((gt & 15) == 15);
        if (bnd) {
            if constexpr (G2) {
                if (grp == 0 && gt == 7) {
                    // publish raw e3 K[0:512) partial (no bias/relu/gate)
#pragma unroll
                    for (int mi = 0; mi < 4; ++mi)
#pragma unroll
                        for (int i = 0; i < 4; ++i) {
                            size_t row = (size_t)(bm * 128 + wr * 64 + mi * 16 + (lane >> 4) * 4 + i);
#pragma unroll
                            for (int ni = 0; ni < 4; ++ni) {
                                __hip_atomic_store(&part3[row * N + bn * 256 + wc * 64 + ni * 16 + ln15],
                                                   acc[mi][ni][i],
                                                   __ATOMIC_RELAXED, __HIP_MEMORY_SCOPE_AGENT);
                                acc[mi][ni][i] = 0.f;
                            }
                        }
                    __syncthreads();
                    if (tid == 0)
                        __hip_atomic_store(&flags[fi], 1, __ATOMIC_RELEASE, __HIP_MEMORY_SCOPE_AGENT);
                } else {
                    int e = (grp == 0) ? ((gt - 8) >> 5) : (4 + (gt >> 5));
                    float bloc[4];
#pragma unroll
                    for (int ni = 0; ni < 4; ++ni)
                        bloc[ni] = bias[e * N + bn * 256 + wc * 64 + ni * 16 + ln15];
#pragma unroll
                    for (int mi = 0; mi < 4; ++mi)
#pragma unroll
                        for (int i = 0; i < 4; ++i) {
                            int row = bm * 128 + wr * 64 + mi * 16 + (lane >> 4) * 4 + i;
                            float g = gate[row * 7 + e];
#pragma unroll
                            for (int ni = 0; ni < 4; ++ni) {
                                fin[mi][ni][i] += g * fmaxf(acc[mi][ni][i] + bloc[ni], 0.f);
                                acc[mi][ni][i] = 0.f;
                            }
                        }
                }
            } else {
                int e = gt >> 4;
                float bloc[4];
#pragma unroll
                for (int ni = 0; ni < 4; ++ni)
                    bloc[ni] = bias[e * N + bn * 256 + wc * 64 + ni * 16 + ln15];
                u16* Hp = (u16*)outp + (size_t)e * M * N;
#pragma unroll
                for (int mi = 0; mi < 4; ++mi)
#pragma unroll
                    for (int i = 0; i < 4; ++i) {
                        size_t row = (size_t)(bm * 128 + wr * 64 + mi * 16 + (lane >> 4) * 4 + i);
#pragma unroll
                        for (int ni = 0; ni < 4; ++ni) {
                            __builtin_nontemporal_store(
                                f2bf(fmaxf(acc[mi][ni][i] + bloc[ni], 0.f)),
                                &Hp[row * N + bn * 256 + wc * 64 + ni * 16 + ln15]);
                            acc[mi][ni][i] = 0.f;
                        }
                    }
            }
        }
    }

    // ---------- final epilogue
    if constexpr (G2) {
        if (grp == 0) {
            // fold e2 happened at gt==103; fin complete -> publish + flagB
#pragma unroll
            for (int mi = 0; mi < 4; ++mi)
#pragma unroll
                for (int i = 0; i < 4; ++i) {
                    size_t row = (size_t)(bm * 128 + wr * 64 + mi * 16 + (lane >> 4) * 4 + i);
#pragma unroll
                    for (int ni = 0; ni < 4; ++ni)
                        __hip_atomic_store(&partF[row * N + bn * 256 + wc * 64 + ni * 16 + ln15],
                                           fin[mi][ni][i],
                                           __ATOMIC_RELAXED, __HIP_MEMORY_SCOPE_AGENT);
                }
            __syncthreads();
            if (tid == 0)
                __hip_atomic_store(&flags[128 + fi], 1, __ATOMIC_RELEASE, __HIP_MEMORY_SCOPE_AGENT);
        } else {
            // acc = own e3 K[512:2048) partial. Merge producer's raw partial PRE-relu.
            if (tid == 0) {
                while (__hip_atomic_load(&flags[fi], __ATOMIC_ACQUIRE, __HIP_MEMORY_SCOPE_AGENT) == 0)
                    __builtin_amdgcn_s_sleep(8);
            }
            __syncthreads();
            {
                float bloc[4];
#pragma unroll
                for (int ni = 0; ni < 4; ++ni)
                    bloc[ni] = bias[3 * N + bn * 256 + wc * 64 + ni * 16 + ln15];
#pragma unroll
                for (int mi = 0; mi < 4; ++mi)
#pragma unroll
                    for (int i = 0; i < 4; ++i) {
                        int row = bm * 128 + wr * 64 + mi * 16 + (lane >> 4) * 4 + i;
                        float g = gate[row * 7 + 3];
#pragma unroll
                        for (int ni = 0; ni < 4; ++ni) {
                            size_t idx = (size_t)row * N + bn * 256 + wc * 64 + ni * 16 + ln15;
                            float full3 = acc[mi][ni][i] +
                                __hip_atomic_load(&part3[idx], __ATOMIC_RELAXED, __HIP_MEMORY_SCOPE_AGENT);
                            fin[mi][ni][i] += g * fmaxf(full3 + bloc[ni], 0.f);
                        }
                    }
            }
            if (tid == 0) {
                while (__hip_atomic_load(&flags[128 + fi], __ATOMIC_ACQUIRE, __HIP_MEMORY_SCOPE_AGENT) == 0)
                    __builtin_amdgcn_s_sleep(8);
            }
            __syncthreads();
            float* out0 = (float*)outp;
#pragma unroll
            for (int mi = 0; mi < 4; ++mi)
#pragma unroll
                for (int i = 0; i < 4; ++i) {
                    size_t row = (size_t)(bm * 128 + wr * 64 + mi * 16 + (lane >> 4) * 4 + i);
#pragma unroll
                    for (int ni = 0; ni < 4; ++ni) {
                        size_t idx = row * N + bn * 256 + wc * 64 + ni * 16 + ln15;
                        float v = fin[mi][ni][i] +
                                  __hip_atomic_load(&partF[idx], __ATOMIC_RELAXED,
                                                    __HIP_MEMORY_SCOPE_AGENT);
                        out0[idx] = v;
                        out0[(size_t)M * N + idx] = v;
                    }
                }
        }
    }
}

extern "C" void kernel_launch(void* const* d_in, const int* in_sizes, int n_in,
                              void* d_out, int out_size, void* d_ws, size_t ws_size,
                              hipStream_t stream) {
    const float* x     = (const float*)d_in[0];
    const int*   scene = (const int*)d_in[1];
    const float* W1    = (const float*)d_in[2];
    const float* b1    = (const float*)d_in[3];
    const float* W2    = (const float*)d_in[4];
    const float* b2    = (const float*)d_in[5];
    const float* S     = (const float*)d_in[6];
    const float* semb  = (const float*)d_in[7];
    float* out = (float*)d_out;

    char* ws = (char*)d_ws;
    // Region [0, 37.7MB) = xb + W1T: live only during gemm1; reused by gemm2 as
    // part3 (16.8MB) + partF (16.8MB) + flags (2KB). flags zeroed post-gemm1.
    float* part3 = (float*)(ws);
    float* partF = (float*)(ws + 16777216);
    int*   flags = (int*)(ws + 33554432);
    u16*   xb    = (u16*)(ws);                                 // 8,388,608 B
    u16*   W1T   = (u16*)(ws + 8388608);                       // 29,360,128 B
    u16*   W2T   = (u16*)(ws + 37748736);                      // 29,360,128 B
    u16*   Hb    = (u16*)(ws + 67108864);                      // 117,440,512 B
    float* gate  = (float*)(ws + 184549376);                   // 114,688 B
    float* ST    = (float*)(ws + 184664064);                   // 216,320 B

    (void)hipFuncSetAttribute(reinterpret_cast<const void*>(gemm8p_kernel<false>),
                              hipFuncAttributeMaxDynamicSharedMemorySize, 98304);
    (void)hipFuncSetAttribute(reinterpret_cast<const void*>(gemm8p_kernel<true>),
                              hipFuncAttributeMaxDynamicSharedMemorySize, 98304);

    transpose_cvt_kernel<<<dim3(32, 16, 7), 256, 0, stream>>>(W1, W1T, 1024, 2048);
    transpose_cvt_kernel<<<dim3(16, 32, 7), 256, 0, stream>>>(W2, W2T, 2048, 1024);
    transpose_S_kernel<<<(1040 * 52 + 255) / 256, 256, 0, stream>>>(S, ST);
    gating_kernel<<<1024, 256, 0, stream>>>(x, scene, ST, semb, gate, xb);
    gemm8p_kernel<false><<<256, 512, 98304, stream>>>(xb, W1T, b1, nullptr, Hb,
                                                      nullptr, nullptr, nullptr);
    (void)hipMemsetAsync(flags, 0, 2048, stream);
    gemm8p_kernel<true><<<256, 512, 98304, stream>>>(Hb, W2T, b2, gate, out,
                                                     part3, partF, flags);
}

// Round 19
// 358.099 us; speedup vs baseline: 1.0925x; 1.0925x over previous
//
#include <hip/hip_runtime.h>
#include <hip/hip_bf16.h>

typedef unsigned short u16;
typedef __bf16 bf8 __attribute__((ext_vector_type(8)));
typedef float f4 __attribute__((ext_vector_type(4)));

__device__ __forceinline__ u16 f2bf(float f) {
    unsigned int u = __float_as_uint(f);
    u = (u + 0x7fffu + ((u >> 16) & 1u)) >> 16;   // RNE
    return (u16)u;
}

__device__ __forceinline__ void gload16(const u16* g, u16* l) {
    __builtin_amdgcn_global_load_lds((const __attribute__((address_space(1))) void*)g,
                                     (__attribute__((address_space(3))) void*)l, 16, 0, 0);
}

// ------------- [E][R][C] f32 -> [E][C][R] bf16, 64x64 tiles -------------
__global__ void transpose_cvt_kernel(const float* __restrict__ in, u16* __restrict__ out,
                                     int R, int C) {
    __shared__ u16 t[64][71];
    int e = blockIdx.z;
    int c0 = blockIdx.x * 64, r0 = blockIdx.y * 64;
    int tid = threadIdx.x;
    const float* ip = in + (size_t)e * R * C;
    u16* op = out + (size_t)e * R * C;
#pragma unroll
    for (int k = 0; k < 16; ++k) {
        int idx = k * 256 + tid;
        int r = idx >> 6, c = idx & 63;
        t[c][r] = f2bf(ip[(size_t)(r0 + r) * C + c0 + c]);
    }
    __syncthreads();
#pragma unroll
    for (int k = 0; k < 8; ++k) {
        int c = k * 8 + (tid >> 5);
        int rr = (tid & 31) * 2;
        ushort2 v = make_ushort2(t[c][rr], t[c][rr + 1]);
        *(ushort2*)(op + (size_t)(c0 + c) * R + r0 + rr) = v;
    }
}

// ---------- S [7][1040][7] -> ST [1040][52] ----------
__global__ void transpose_S_kernel(const float* __restrict__ S, float* __restrict__ ST) {
    int idx = blockIdx.x * 256 + threadIdx.x;
    if (idx >= 1040 * 52) return;
    int d = idx / 52, c = idx % 52;
    ST[idx] = (c < 49) ? S[(c / 7) * 7280 + d * 7 + (c % 7)] : 0.f;
}

// ---------------- gating (fp32, exact semantics) + fused x->bf16 ----------------
__global__ void gating_kernel(const float* __restrict__ x, const int* __restrict__ scene,
                              const float* __restrict__ ST, const float* __restrict__ semb,
                              float* __restrict__ gate, u16* __restrict__ xb) {
    __shared__ float xc[4][1040];
    __shared__ float Lsh[4][49];
    int wv = threadIdx.x >> 6, lane = threadIdx.x & 63;
    int row = blockIdx.x * 4 + wv;
    float* xcw = xc[wv];
    const float* xr = x + (size_t)row * 1024;
    for (int d = lane; d < 1024; d += 64) xcw[d] = xr[d];
    int sc = scene[row];
    if (lane < 16) xcw[1024 + lane] = semb[sc * 16 + lane];
    __syncthreads();

    // fused cvt_x: emit bf16 row from staged LDS copy
    u16* xrow = xb + (size_t)row * 1024;
    for (int d = lane * 4; d < 1024; d += 256) {
        ushort4 o;
        o.x = f2bf(xcw[d]);     o.y = f2bf(xcw[d + 1]);
        o.z = f2bf(xcw[d + 2]); o.w = f2bf(xcw[d + 3]);
        *(ushort4*)(xrow + d) = o;
    }

    if (lane < 49) {
        const float* STp = ST + lane;
        float a0 = 0.f, a1 = 0.f, a2 = 0.f, a3 = 0.f;
        for (int d = 0; d < 1040; d += 4) {
            a0 += xcw[d]     * STp[d * 52];
            a1 += xcw[d + 1] * STp[d * 52 + 52];
            a2 += xcw[d + 2] * STp[d * 52 + 104];
            a3 += xcw[d + 3] * STp[d * 52 + 156];
        }
        Lsh[wv][lane] = (a0 + a1) + (a2 + a3);
    }
    __syncthreads();

    if (lane == 0) {
        float logG[7][7], Gsc[7], piS[7], qS[7];
        for (int e = 0; e < 7; e++) {
            float L[7];
            float m = -1e30f;
            for (int s = 0; s < 7; s++) { L[s] = Lsh[wv][s * 7 + e]; m = fmaxf(m, L[s]); }
            float sum = 0.f;
            for (int s = 0; s < 7; s++) sum += expf(L[s] - m);
            float lse = m + logf(sum);
            float qs = 0.f;
            for (int s = 0; s < 7; s++) { logG[e][s] = L[s] - lse; qs += logG[e][s]; }
            piS[e] = logG[e][sc];
            qS[e] = qs;
            Gsc[e] = expf(logG[e][sc]);
        }
        int epi = 0, eqi = 0; float bp = piS[0], bq = qS[0];
        for (int e = 1; e < 7; e++) {
            if (piS[e] <= bp) { bp = piS[e]; epi = e; }
            if (qS[e]  <= bq) { bq = qS[e];  eqi = e; }
        }
        float mg = -1e30f;
        for (int e = 0; e < 7; e++) mg = fmaxf(mg, Gsc[e]);
        float sum = 0.f;
        float ex[7];
        for (int e = 0; e < 7; e++) { ex[e] = expf(Gsc[e] - mg); sum += ex[e]; }
        float inv = 1.f / sum;
        for (int e = 0; e < 7; e++) {
            float g = ex[e] * inv;
            if (e == epi && e == eqi) g = 0.f;
            gate[row * 7 + e] = g;
        }
    }
}

// ================= 8-phase GEMM template (R6-proven structure, persistent) ======
// BM=128, BN=256, BK=64, 512 thr (8 waves 2x4), per-wave 64x64.
// LDS per dbuf: A[128][64] + B[256][64]; 2 dbuf = 96KB -> 1 block/CU, grid 256
// = all blocks co-resident (required for the G2 producer-consumer handoff).
// T2 swizzle (full 3-bit): elem col ^= (row&7)<<3; conflicts = 0 (R6-verified).
// Counted vmcnt: 6 loads/K-tile staged (4 at p0, 2 at p1); vmcnt(4) once per
// K-tile, vmcnt(0) only at final tile. Experts CHAINED per block.
// G1: nE=7, per-expert mid-loop nt-store of the H-slab.
// G2: producer group = experts {0,1,2} (finishes ~38us early) -> AGENT-scope
//     stores of partial + release flag; consumer group = experts {3..6} ->
//     acquire flag (already set; spin ~0), add partial, write both T-slices.
template<bool G2>
__global__ __launch_bounds__(512, 2) void gemm8p_kernel(
    const u16* __restrict__ Abase, const u16* __restrict__ Bbase,
    const float* __restrict__ bias, const float* __restrict__ gate,
    void* __restrict__ outp, float* __restrict__ part, int* __restrict__ flags)
{
    constexpr int M = 4096;
    constexpr int K = G2 ? 2048 : 1024;
    constexpr int N = G2 ? 1024 : 2048;
    constexpr int NT = K / 64;
    constexpr int LOG2NT = G2 ? 5 : 4;

    extern __shared__ u16 lds[];

    const int tid = threadIdx.x;
    const int lane = tid & 63;
    const int wid = tid >> 6;
    const int wr = wid >> 2, wc = wid & 3;
    const int ln15 = lane & 15, lnk = (lane >> 4) * 8;

    int bm, bn, e0, nE, grp;
    if constexpr (G2) {
        int id = blockIdx.x;
        int xcd = id & 7, slot = id >> 3;
        grp = xcd & 1;                  // 0: producer (3 experts), 1: consumer (4)
        bn = slot & 3;
        bm = (slot >> 2) * 4 + (xcd >> 1);
        e0 = grp ? 3 : 0; nE = grp ? 4 : 3;
    } else {
        // persistent: 256 blocks = 32 bm x 8 bn, same-bm blocks share an XCD
        int xcd = blockIdx.x & 7, slot = blockIdx.x >> 3;
        bn = slot >> 2;
        bm = (slot & 3) * 8 + xcd;
        e0 = 0; nE = 7; grp = 0;
    }
    const int NTtot = nE * NT;

    const int sr = tid >> 3;          // staging row within 64-row sub-unit
    const int sc = (tid & 7) * 8;     // staging col (elems)

    auto stageA = [&](int gt, int buf) {
#pragma unroll
        for (int l = 0; l < 2; ++l) {
            int r = l * 64 + sr;
            int cs = sc ^ ((r & 7) << 3);
            const u16* g = Abase + (G2 ? (size_t)(e0 + (gt >> LOG2NT)) * M * K : (size_t)0)
                         + (size_t)(bm * 128 + r) * K + (gt & (NT - 1)) * 64 + cs;
            gload16(g, lds + buf * 24576 + l * 4096 + tid * 8);
        }
    };
    auto stageB = [&](int gt, int buf, int h) {
#pragma unroll
        for (int l = 0; l < 2; ++l) {
            int rb = h * 128 + l * 64 + sr;
            int cs = sc ^ ((rb & 7) << 3);
            const u16* g = Bbase + (size_t)(e0 + (gt >> LOG2NT)) * N * K
                         + (size_t)(bn * 256 + rb) * K + (gt & (NT - 1)) * 64 + cs;
            gload16(g, lds + buf * 24576 + 8192 + h * 8192 + l * 4096 + tid * 8);
        }
    };
    auto aoff = [&](int mi, int ks) {
        int r = wr * 64 + mi * 16 + ln15;
        int c = ks * 32 + lnk;
        return r * 64 + (c ^ ((r & 7) << 3));
    };
    auto boff = [&](int ni, int ks) {
        int rb = wc * 64 + ni * 16 + ln15;
        int c = ks * 32 + lnk;
        return rb * 64 + (c ^ ((rb & 7) << 3));
    };

    f4 acc[4][4] = {};
    f4 fin[4][4] = {};
    bf8 aA[2][2], bL[2][2], bH[2][2];

    // prologue: tile 0 into buf 0 (6 loads)
    stageA(0, 0); stageB(0, 0, 0); stageB(0, 0, 1);

    for (int gt = 0; gt < NTtot; ++gt) {
        const int cur = gt & 1, nxt = cur ^ 1;
        const bool more = (gt + 1 < NTtot);
        const u16* Ac = lds + cur * 24576;
        const u16* Bc = lds + cur * 24576 + 8192;
        // ---------- phase 0: stage(A',B0') + wait tile gt + Q(m-lo, n-lo)
        if (more) {
            stageA(gt + 1, nxt); stageB(gt + 1, nxt, 0);
            asm volatile("s_waitcnt vmcnt(4)" ::: "memory");
        } else {
            asm volatile("s_waitcnt vmcnt(0)" ::: "memory");
        }
        __builtin_amdgcn_sched_barrier(0);
        __builtin_amdgcn_s_barrier();
        __builtin_amdgcn_sched_barrier(0);
#pragma unroll
        for (int mi = 0; mi < 2; ++mi)
#pragma unroll
            for (int ks = 0; ks < 2; ++ks)
                aA[mi][ks] = *(const bf8*)(Ac + aoff(mi, ks));
#pragma unroll
        for (int ni = 0; ni < 2; ++ni)
#pragma unroll
            for (int ks = 0; ks < 2; ++ks)
                bL[ni][ks] = *(const bf8*)(Bc + boff(ni, ks));
        asm volatile("s_waitcnt lgkmcnt(0)" ::: "memory");
        __builtin_amdgcn_sched_barrier(0);
        __builtin_amdgcn_s_setprio(1);
#pragma unroll
        for (int mi = 0; mi < 2; ++mi)
#pragma unroll
            for (int ni = 0; ni < 2; ++ni)
#pragma unroll
                for (int ks = 0; ks < 2; ++ks)
                    acc[mi][ni] = __builtin_amdgcn_mfma_f32_16x16x32_bf16(aA[mi][ks], bL[ni][ks], acc[mi][ni], 0, 0, 0);
        __builtin_amdgcn_s_setprio(0);
        // ---------- phase 1: stage(B1') + Q(m-lo, n-hi)
        if (more) stageB(gt + 1, nxt, 1);
#pragma unroll
        for (int ni = 0; ni < 2; ++ni)
#pragma unroll
            for (int ks = 0; ks < 2; ++ks)
                bH[ni][ks] = *(const bf8*)(Bc + boff(2 + ni, ks));
        asm volatile("s_waitcnt lgkmcnt(0)" ::: "memory");
        __builtin_amdgcn_sched_barrier(0);
        __builtin_amdgcn_s_setprio(1);
#pragma unroll
        for (int mi = 0; mi < 2; ++mi)
#pragma unroll
            for (int ni = 0; ni < 2; ++ni)
#pragma unroll
                for (int ks = 0; ks < 2; ++ks)
                    acc[mi][2 + ni] = __builtin_amdgcn_mfma_f32_16x16x32_bf16(aA[mi][ks], bH[ni][ks], acc[mi][2 + ni], 0, 0, 0);
        __builtin_amdgcn_s_setprio(0);
        // ---------- phase 2: reload A (m-hi) + Q(m-hi, n-hi)
#pragma unroll
        for (int mi = 0; mi < 2; ++mi)
#pragma unroll
            for (int ks = 0; ks < 2; ++ks)
                aA[mi][ks] = *(const bf8*)(Ac + aoff(2 + mi, ks));
        asm volatile("s_waitcnt lgkmcnt(0)" ::: "memory");
        __builtin_amdgcn_sched_barrier(0);
        __builtin_amdgcn_s_setprio(1);
#pragma unroll
        for (int mi = 0; mi < 2; ++mi)
#pragma unroll
            for (int ni = 0; ni < 2; ++ni)
#pragma unroll
                for (int ks = 0; ks < 2; ++ks)
                    acc[2 + mi][2 + ni] = __builtin_amdgcn_mfma_f32_16x16x32_bf16(aA[mi][ks], bH[ni][ks], acc[2 + mi][2 + ni], 0, 0, 0);
        __builtin_amdgcn_s_setprio(0);
        // ---------- phase 3: barrier (protect buf[cur] before gt+2 stages) + Q(m-hi, n-lo)
        __builtin_amdgcn_sched_barrier(0);
        __builtin_amdgcn_s_barrier();
        __builtin_amdgcn_sched_barrier(0);
        __builtin_amdgcn_s_setprio(1);
#pragma unroll
        for (int mi = 0; mi < 2; ++mi)
#pragma unroll
            for (int ni = 0; ni < 2; ++ni)
#pragma unroll
                for (int ks = 0; ks < 2; ++ks)
                    acc[2 + mi][ni] = __builtin_amdgcn_mfma_f32_16x16x32_bf16(aA[mi][ks], bL[ni][ks], acc[2 + mi][ni], 0, 0, 0);
        __builtin_amdgcn_s_setprio(0);
        __builtin_amdgcn_sched_barrier(0);
        // ---------- expert boundary: per-expert epilogue, reset acc
        if ((gt & (NT - 1)) == NT - 1) {
            int e = e0 + (gt >> LOG2NT);
            float bloc[4];
#pragma unroll
            for (int ni = 0; ni < 4; ++ni)
                bloc[ni] = bias[e * N + bn * 256 + wc * 64 + ni * 16 + ln15];
            if constexpr (G2) {
#pragma unroll
                for (int mi = 0; mi < 4; ++mi)
#pragma unroll
                    for (int i = 0; i < 4; ++i) {
                        int row = bm * 128 + wr * 64 + mi * 16 + (lane >> 4) * 4 + i;
                        float g = gate[row * 7 + e];
#pragma unroll
                        for (int ni = 0; ni < 4; ++ni) {
                            fin[mi][ni][i] += g * fmaxf(acc[mi][ni][i] + bloc[ni], 0.f);
                            acc[mi][ni][i] = 0.f;
                        }
                    }
            } else {
                u16* Hp = (u16*)outp + (size_t)e * M * N;
#pragma unroll
                for (int mi = 0; mi < 4; ++mi)
#pragma unroll
                    for (int i = 0; i < 4; ++i) {
                        size_t row = (size_t)(bm * 128 + wr * 64 + mi * 16 + (lane >> 4) * 4 + i);
#pragma unroll
                        for (int ni = 0; ni < 4; ++ni) {
                            // nt: keep the 117MB H stream out of L3 so x/W1T stay resident
                            __builtin_nontemporal_store(
                                f2bf(fmaxf(acc[mi][ni][i] + bloc[ni], 0.f)),
                                &Hp[row * N + bn * 256 + wc * 64 + ni * 16 + ln15]);
                            acc[mi][ni][i] = 0.f;
                        }
                    }
            }
        }
    }

    // ---------- final epilogue (G2 only; G1 wrote per-expert slabs in-loop)
    if constexpr (G2) {
        const int fi = bm * 4 + bn;
        if (grp == 0) {
            // producer: publish partial with AGENT-scope stores (cross-XCD safe,
            // replay-safe: no reliance on non-coherent L2 lines)
#pragma unroll
            for (int mi = 0; mi < 4; ++mi)
#pragma unroll
                for (int i = 0; i < 4; ++i) {
                    size_t row = (size_t)(bm * 128 + wr * 64 + mi * 16 + (lane >> 4) * 4 + i);
#pragma unroll
                    for (int ni = 0; ni < 4; ++ni)
                        __hip_atomic_store(&part[row * N + bn * 256 + wc * 64 + ni * 16 + ln15],
                                           fin[mi][ni][i],
                                           __ATOMIC_RELAXED, __HIP_MEMORY_SCOPE_AGENT);
                }
            __syncthreads();          // all threads' stores happen-before flag
            if (tid == 0)
                __hip_atomic_store(&flags[fi], 1, __ATOMIC_RELEASE, __HIP_MEMORY_SCOPE_AGENT);
        } else {
            // consumer (finishes ~38us later): flag is already set; spin ~never taken
            if (tid == 0) {
                while (__hip_atomic_load(&flags[fi], __ATOMIC_ACQUIRE, __HIP_MEMORY_SCOPE_AGENT) == 0)
                    __builtin_amdgcn_s_sleep(8);
            }
            __syncthreads();
            float* out0 = (float*)outp;
#pragma unroll
            for (int mi = 0; mi < 4; ++mi)
#pragma unroll
                for (int i = 0; i < 4; ++i) {
                    size_t row = (size_t)(bm * 128 + wr * 64 + mi * 16 + (lane >> 4) * 4 + i);
#pragma unroll
                    for (int ni = 0; ni < 4; ++ni) {
                        size_t idx = row * N + bn * 256 + wc * 64 + ni * 16 + ln15;
                        float v = fin[mi][ni][i] +
                                  __hip_atomic_load(&part[idx], __ATOMIC_RELAXED,
                                                    __HIP_MEMORY_SCOPE_AGENT);
                        out0[idx] = v;
                        out0[(size_t)M * N + idx] = v;
                    }
                }
        }
    }
}

extern "C" void kernel_launch(void* const* d_in, const int* in_sizes, int n_in,
                              void* d_out, int out_size, void* d_ws, size_t ws_size,
                              hipStream_t stream) {
    const float* x     = (const float*)d_in[0];
    const int*   scene = (const int*)d_in[1];
    const float* W1    = (const float*)d_in[2];
    const float* b1    = (const float*)d_in[3];
    const float* W2    = (const float*)d_in[4];
    const float* b2    = (const float*)d_in[5];
    const float* S     = (const float*)d_in[6];
    const float* semb  = (const float*)d_in[7];
    float* out = (float*)d_out;

    char* ws = (char*)d_ws;
    // Region [0, 37.7MB) = xb + W1T: live only during gemm1; reused by gemm2 as
    // part (16.8MB) + flags (512B). flags zeroed post-gemm1 (stream-ordered).
    float* part  = (float*)(ws);
    u16*   xb    = (u16*)(ws);                                 // 8,388,608 B
    u16*   W1T   = (u16*)(ws + 8388608);                       // 29,360,128 B
    int*   flags = (int*)(ws + 16777216);                      // 512 B
    u16*   W2T   = (u16*)(ws + 37748736);                      // 29,360,128 B
    u16*   Hb    = (u16*)(ws + 67108864);                      // 117,440,512 B
    float* gate  = (float*)(ws + 184549376);                   // 114,688 B
    float* ST    = (float*)(ws + 184664064);                   // 216,320 B

    (void)hipFuncSetAttribute(reinterpret_cast<const void*>(gemm8p_kernel<false>),
                              hipFuncAttributeMaxDynamicSharedMemorySize, 98304);
    (void)hipFuncSetAttribute(reinterpret_cast<const void*>(gemm8p_kernel<true>),
                              hipFuncAttributeMaxDynamicSharedMemorySize, 98304);

    transpose_cvt_kernel<<<dim3(32, 16, 7), 256, 0, stream>>>(W1, W1T, 1024, 2048);
    transpose_cvt_kernel<<<dim3(16, 32, 7), 256, 0, stream>>>(W2, W2T, 2048, 1024);
    transpose_S_kernel<<<(1040 * 52 + 255) / 256, 256, 0, stream>>>(S, ST);
    gating_kernel<<<1024, 256, 0, stream>>>(x, scene, ST, semb, gate, xb);
    gemm8p_kernel<false><<<256, 512, 98304, stream>>>(xb, W1T, b1, nullptr, Hb, nullptr, nullptr);
    (void)hipMemsetAsync(flags, 0, 512, stream);
    gemm8p_kernel<true><<<256, 512, 98304, stream>>>(Hb, W2T, b2, gate, out, part, flags);
}